// Round 4
// baseline (636.637 us; speedup 1.0000x reference)
//
#include <hip/hip_runtime.h>
#include <hip/hip_bf16.h>

// MultiHeadAttention fused pipeline for MI355X (gfx950).
// b=2, t=s=2048, E=1024, H=16, D=64. Outputs: out fp32 [2,2048,1024], attn fp32 [32,2048,2048].

typedef __attribute__((ext_vector_type(8))) __bf16 bf16x8;
typedef __attribute__((ext_vector_type(4))) float f32x4;
typedef __attribute__((ext_vector_type(8))) unsigned short us8;

#define MFMA16(A, B, C) __builtin_amdgcn_mfma_f32_16x16x32_bf16(A, B, C, 0, 0, 0)

__device__ __forceinline__ unsigned short f2bf(float f) {
  __bf16 h = (__bf16)f;
  return __builtin_bit_cast(unsigned short, h);
}

// ---------------- fused fp32 -> bf16 convert for all 7 tensors ----------------
__global__ __launch_bounds__(256) void cvt_all_kernel(
    const float* __restrict__ q, const float* __restrict__ k, const float* __restrict__ v,
    const float* __restrict__ Wq, const float* __restrict__ Wk,
    const float* __restrict__ Wv, const float* __restrict__ Wo,
    unsigned short* __restrict__ qb, unsigned short* __restrict__ kb,
    unsigned short* __restrict__ vb, unsigned short* __restrict__ wqb,
    unsigned short* __restrict__ wkb, unsigned short* __restrict__ wvb,
    unsigned short* __restrict__ wob) {
  const int bid = blockIdx.x;
  const float* src;
  unsigned short* dst;
  int i;
  if (bid < 4096)       { src = q; dst = qb; i = bid * 256 + threadIdx.x; }
  else if (bid < 8192)  { src = k; dst = kb; i = (bid - 4096) * 256 + threadIdx.x; }
  else if (bid < 12288) { src = v; dst = vb; i = (bid - 8192) * 256 + threadIdx.x; }
  else {
    int wsel = (bid - 12288) >> 10;
    i = ((bid - 12288) & 1023) * 256 + threadIdx.x;
    src = wsel == 0 ? Wq : wsel == 1 ? Wk : wsel == 2 ? Wv : Wo;
    dst = wsel == 0 ? wqb : wsel == 1 ? wkb : wsel == 2 ? wvb : wob;
  }
  float4 vv = ((const float4*)src)[i];
  ushort4 o;
  o.x = f2bf(vv.x); o.y = f2bf(vv.y); o.z = f2bf(vv.z); o.w = f2bf(vv.w);
  ((ushort4*)dst)[i] = o;
}

// ---------------- GEMM: C[M][1024] = A[M][1024] @ W[1024][1024]^T + bias, *scale ----------
// 128x64 tile, BK=64, 4 waves (each 32x64). Grid (M/128, 16) = 512 blocks -> 2 blocks/CU.
template <bool OUT_F32>
__global__ __launch_bounds__(256) void gemm_bt_kernel(
    const unsigned short* __restrict__ A,   // [M][1024] bf16
    const unsigned short* __restrict__ Bw,  // [1024][1024] bf16 (row n = weights of out col n)
    const float* __restrict__ bias,         // [1024] fp32
    void* __restrict__ Cout,                // [M][1024] bf16 or fp32
    float scale) {
  __shared__ short As[128 * 72];
  __shared__ short Bs[64 * 72];
  const int tid = threadIdx.x;
  const int l = tid & 63, w = tid >> 6;
  const int lq = l >> 4, lr = l & 15;
  const int m0 = blockIdx.x * 128, n0 = blockIdx.y * 64;

  uint4 va[4], vb[2];
#pragma unroll
  for (int i = 0; i < 4; ++i) {
    int c = i * 256 + tid, r = c >> 3, c8 = c & 7;
    va[i] = *(const uint4*)(A + (size_t)(m0 + r) * 1024 + c8 * 8);
  }
#pragma unroll
  for (int i = 0; i < 2; ++i) {
    int c = i * 256 + tid, r = c >> 3, c8 = c & 7;
    vb[i] = *(const uint4*)(Bw + (size_t)(n0 + r) * 1024 + c8 * 8);
  }
  const f32x4 fz = {0.f, 0.f, 0.f, 0.f};
  f32x4 acc[2][4];
#pragma unroll
  for (int m = 0; m < 2; ++m)
#pragma unroll
    for (int n = 0; n < 4; ++n) acc[m][n] = fz;

  for (int ks = 0; ks < 16; ++ks) {
    __syncthreads();
#pragma unroll
    for (int i = 0; i < 4; ++i) {
      int c = i * 256 + tid, r = c >> 3, c8 = c & 7;
      *(uint4*)((char*)As + r * 144 + c8 * 16) = va[i];
    }
#pragma unroll
    for (int i = 0; i < 2; ++i) {
      int c = i * 256 + tid, r = c >> 3, c8 = c & 7;
      *(uint4*)((char*)Bs + r * 144 + c8 * 16) = vb[i];
    }
    __syncthreads();
    if (ks < 15) {
      int k0 = (ks + 1) * 64;
#pragma unroll
      for (int i = 0; i < 4; ++i) {
        int c = i * 256 + tid, r = c >> 3, c8 = c & 7;
        va[i] = *(const uint4*)(A + (size_t)(m0 + r) * 1024 + k0 + c8 * 8);
      }
#pragma unroll
      for (int i = 0; i < 2; ++i) {
        int c = i * 256 + tid, r = c >> 3, c8 = c & 7;
        vb[i] = *(const uint4*)(Bw + (size_t)(n0 + r) * 1024 + k0 + c8 * 8);
      }
    }
#pragma unroll
    for (int kk = 0; kk < 2; ++kk) {
      bf16x8 af[2], bfr[4];
#pragma unroll
      for (int m = 0; m < 2; ++m)
        af[m] = *(const bf16x8*)((const char*)As + (w * 32 + m * 16 + lr) * 144 + kk * 64 + lq * 16);
#pragma unroll
      for (int n = 0; n < 4; ++n)
        bfr[n] = *(const bf16x8*)((const char*)Bs + (n * 16 + lr) * 144 + kk * 64 + lq * 16);
#pragma unroll
      for (int m = 0; m < 2; ++m)
#pragma unroll
        for (int n = 0; n < 4; ++n) acc[m][n] = MFMA16(af[m], bfr[n], acc[m][n]);
    }
  }
  // epilogue: C row = (lane>>4)*4+reg, col = lane&15
#pragma unroll
  for (int n = 0; n < 4; ++n) {
    const int col = n0 + n * 16 + lr;
    const float bv_ = bias[col];
#pragma unroll
    for (int m = 0; m < 2; ++m) {
      const int rowb = m0 + w * 32 + m * 16 + lq * 4;
#pragma unroll
      for (int r = 0; r < 4; ++r) {
        float vv = (acc[m][n][r] + bv_) * scale;
        if (OUT_F32)
          ((float*)Cout)[(size_t)(rowb + r) * 1024 + col] = vv;
        else
          ((unsigned short*)Cout)[(size_t)(rowb + r) * 1024 + col] = f2bf(vv);
      }
    }
  }
}

// ---------------- V' [b*2048+key][h*64+d] -> Vt [(b*16+h)*64+d][key] ----------------
__global__ __launch_bounds__(256) void transpose_v_kernel(const unsigned short* __restrict__ Vp,
                                                          unsigned short* __restrict__ Vt) {
  __shared__ unsigned short Ts[64 * 72];
  const int tid = threadIdx.x;
  const int kt = blockIdx.x;  // key tile 0..31
  const int rt = blockIdx.y;  // (b*16+h) 0..31
  const int b_ = rt >> 4, h_ = rt & 15;
#pragma unroll
  for (int i = 0; i < 2; ++i) {
    int c = i * 256 + tid, r = c >> 3, c8 = c & 7;
    uint4 v = *(const uint4*)(Vp + (size_t)(b_ * 2048 + kt * 64 + r) * 1024 + h_ * 64 + c8 * 8);
    *(uint4*)((char*)Ts + r * 144 + c8 * 16) = v;
  }
  __syncthreads();
#pragma unroll
  for (int i = 0; i < 2; ++i) {
    int c = i * 256 + tid, dr = c >> 3, k8 = c & 7;
    us8 t8;
#pragma unroll
    for (int j = 0; j < 8; ++j) t8[j] = Ts[(k8 * 8 + j) * 72 + dr];
    *(us8*)(Vt + (size_t)(rt * 64 + dr) * 2048 + kt * 64 + k8 * 8) = t8;
  }
}

// ---------------- fused attention ----------------
// block = (b,h, 64 query rows); 4 waves x 16 rows. Two passes over 32 key-chunks of 64.
// K and V are read directly from global as MFMA B-fragments (L1/L2-resident, 256 KB per
// head) -- no LDS staging, no staging barriers. Pass A (denominators) is barrier-free.
// Pass B: recompute S, write normalized P fp32 into XOR-swizzled Pf, barrier, coalesced
// nontemporal full-line stores + PV MFMA (A-frag re-read from Pf, cvt to bf16), barrier.
// LDS 24576 B -> 6 blocks/CU. Additive mask preloaded once (8 KB).
__device__ __forceinline__ int pf_idx(int row, int col) {
  return row * 64 + (((col >> 2) ^ (row & 7)) << 2) + (col & 3);
}

__global__ __launch_bounds__(256) void attn_kernel(
    const unsigned short* __restrict__ Qp,  // [4096][1024] bf16 (pre-scaled)
    const unsigned short* __restrict__ Kp,  // [4096][1024] bf16
    const unsigned short* __restrict__ Vt,  // [2048][2048] bf16, row=(b*16+h)*64+d, col=key
    const int* __restrict__ mask,           // [2][2048]
    float* __restrict__ attn_out,           // [32][2048][2048] fp32
    unsigned short* __restrict__ Obuf)      // [4096][1024] bf16
{
  __shared__ char smem[24576];
  float* Pf = (float*)smem;                 // 16384 B (pass B); Qs overlaps (init only)
  short* Qs = (short*)smem;                 // 9216 B
  float* maskadd = (float*)(smem + 16384);  // 8192 B

  const int tid = threadIdx.x;
  const int l = tid & 63, w = tid >> 6;
  const int lq = l >> 4, lr = l & 15;
  const int tb = blockIdx.x, h = blockIdx.y, bz = blockIdx.z;

  const size_t qrow0 = (size_t)bz * 2048 + tb * 64;
  const size_t krow0 = (size_t)bz * 2048;
  const size_t vrow0 = (size_t)(bz * 16 + h) * 64;

  // preload additive mask for the whole key range
  for (int j = tid; j < 2048; j += 256) {
    int mv = mask[bz * 2048 + j];
    maskadd[j] = (mv == 0) ? -9.0e15f : (float)mv;
  }
  // stage Q block [64][64] -> Qs (stride 72), then pull fragments to registers
#pragma unroll
  for (int i = 0; i < 2; ++i) {
    int c = i * 256 + tid, r = c >> 3, c8 = c & 7;
    uint4 v = *(const uint4*)(Qp + (qrow0 + r) * 1024 + h * 64 + c8 * 8);
    *(uint4*)((char*)Qs + r * 144 + c8 * 16) = v;
  }
  __syncthreads();
  bf16x8 aq[2];
#pragma unroll
  for (int kk = 0; kk < 2; ++kk)
    aq[kk] = *(const bf16x8*)((const char*)Qs + (w * 16 + lr) * 144 + kk * 64 + lq * 16);
  __syncthreads();  // Qs dead; Pf may be written from here on

  const unsigned short* kbase = Kp + krow0 * 1024 + h * 64;

  // ---------- pass A: denominators (barrier-free) ----------
  float lacc[4] = {0.f, 0.f, 0.f, 0.f};
  for (int kc = 0; kc < 32; ++kc) {
#pragma unroll
    for (int jt = 0; jt < 4; ++jt) {
      f32x4 sa = {0.f, 0.f, 0.f, 0.f};
#pragma unroll
      for (int kk = 0; kk < 2; ++kk) {
        bf16x8 bk = *(const bf16x8*)(kbase + (size_t)(kc * 64 + jt * 16 + lr) * 1024 + kk * 32 + lq * 8);
        sa = MFMA16(aq[kk], bk, sa);
      }
      float ma = maskadd[kc * 64 + jt * 16 + lr];
#pragma unroll
      for (int r = 0; r < 4; ++r) {
        float s_ = fminf(fmaxf(sa[r], -50000.f), 50000.f) + ma;
        lacc[r] += __expf(s_);
      }
    }
  }
#pragma unroll
  for (int r = 0; r < 4; ++r) {
    float t = lacc[r];
    t += __shfl_xor(t, 1, 64);
    t += __shfl_xor(t, 2, 64);
    t += __shfl_xor(t, 4, 64);
    t += __shfl_xor(t, 8, 64);
    lacc[r] = 1.0f / t;  // reciprocal denominator for row lq*4+r
  }

  // ---------- pass B: write attn (coalesced via Pf) + PV ----------
  const f32x4 fz = {0.f, 0.f, 0.f, 0.f};
  f32x4 oacc[4];
#pragma unroll
  for (int dt = 0; dt < 4; ++dt) oacc[dt] = fz;
  const size_t arow = (size_t)(bz * 16 + h) * 2048 + tb * 64;
  for (int kc = 0; kc < 32; ++kc) {
#pragma unroll
    for (int jt = 0; jt < 4; ++jt) {
      f32x4 sa = {0.f, 0.f, 0.f, 0.f};
#pragma unroll
      for (int kk = 0; kk < 2; ++kk) {
        bf16x8 bk = *(const bf16x8*)(kbase + (size_t)(kc * 64 + jt * 16 + lr) * 1024 + kk * 32 + lq * 8);
        sa = MFMA16(aq[kk], bk, sa);
      }
      float ma = maskadd[kc * 64 + jt * 16 + lr];
#pragma unroll
      for (int r = 0; r < 4; ++r) {
        float s_ = fminf(fmaxf(sa[r], -50000.f), 50000.f) + ma;
        float p = __expf(s_) * lacc[r];
        Pf[pf_idx(w * 16 + lq * 4 + r, jt * 16 + lr)] = p;
      }
    }
    __syncthreads();  // Pf complete
    // cooperative full-line nontemporal stores: 4 KB contiguous per block-iteration
#pragma unroll
    for (int it = 0; it < 4; ++it) {
      int idx = it * 256 + tid, row = idx >> 4, c4 = idx & 15;
      f32x4 pv4 = *(const f32x4*)&Pf[pf_idx(row, c4 * 4)];
      f32x4* dst = (f32x4*)&attn_out[(arow + row) * 2048 + kc * 64 + c4 * 4];
      __builtin_nontemporal_store(pv4, dst);
    }
    // PV: A-frag = P rows (this wave's own 16 rows) from Pf, cvt fp32->bf16; B = Vt global
#pragma unroll
    for (int kk = 0; kk < 2; ++kk) {
      const int prow = w * 16 + lr;
      f32x4 a0 = *(const f32x4*)&Pf[pf_idx(prow, kk * 32 + lq * 8)];
      f32x4 a1 = *(const f32x4*)&Pf[pf_idx(prow, kk * 32 + lq * 8 + 4)];
      bf16x8 ap;
#pragma unroll
      for (int j = 0; j < 4; ++j) {
        ap[j] = (__bf16)a0[j];
        ap[4 + j] = (__bf16)a1[j];
      }
#pragma unroll
      for (int dt = 0; dt < 4; ++dt) {
        bf16x8 bv_ = *(const bf16x8*)(Vt + (vrow0 + dt * 16 + lr) * 2048 + kc * 64 + kk * 32 + lq * 8);
        oacc[dt] = MFMA16(ap, bv_, oacc[dt]);
      }
    }
    __syncthreads();  // all Pf reads done before next-iteration writes
  }
  // write O (bf16) in [b*2048+t][h*64+d] layout for the final projection
#pragma unroll
  for (int dt = 0; dt < 4; ++dt) {
    int col = h * 64 + dt * 16 + lr;
#pragma unroll
    for (int r = 0; r < 4; ++r) {
      int trow = tb * 64 + w * 16 + lq * 4 + r;
      Obuf[((size_t)bz * 2048 + trow) * 1024 + col] = f2bf(oacc[dt][r]);
    }
  }
}

extern "C" void kernel_launch(void* const* d_in, const int* in_sizes, int n_in,
                              void* d_out, int out_size, void* d_ws, size_t ws_size,
                              hipStream_t stream) {
  (void)in_sizes; (void)n_in; (void)out_size; (void)ws_size;
  const float* q  = (const float*)d_in[0];
  const float* k  = (const float*)d_in[1];
  const float* v  = (const float*)d_in[2];
  const int* msk  = (const int*)d_in[3];
  const float* Wq = (const float*)d_in[4];
  const float* bq = (const float*)d_in[5];
  const float* Wk = (const float*)d_in[6];
  const float* bk = (const float*)d_in[7];
  const float* Wv = (const float*)d_in[8];
  const float* bv = (const float*)d_in[9];
  const float* Wo = (const float*)d_in[10];
  const float* bo = (const float*)d_in[11];

  // workspace layout (bf16 elements), total ~72 MB
  unsigned short* p = (unsigned short*)d_ws;
  unsigned short* qb  = p; p += 4194304;
  unsigned short* kb  = p; p += 4194304;
  unsigned short* vb  = p; p += 4194304;
  unsigned short* wqb = p; p += 1048576;
  unsigned short* wkb = p; p += 1048576;
  unsigned short* wvb = p; p += 1048576;
  unsigned short* wob = p; p += 1048576;
  unsigned short* Qp  = p; p += 4194304;
  unsigned short* Kp  = p; p += 4194304;
  unsigned short* Vp  = p; p += 4194304;
  unsigned short* Vtg = p; p += 4194304;
  unsigned short* Ob  = p; p += 4194304;

  cvt_all_kernel<<<16384, 256, 0, stream>>>(q, k, v, Wq, Wk, Wv, Wo,
                                            qb, kb, vb, wqb, wkb, wvb, wob);

  dim3 gg(32, 16);
  const float scale = 0.125f;  // HEAD_DIM^-0.5
  gemm_bt_kernel<false><<<gg, 256, 0, stream>>>(qb, wqb, bq, Qp, scale);
  gemm_bt_kernel<false><<<gg, 256, 0, stream>>>(kb, wkb, bk, Kp, 1.0f);
  gemm_bt_kernel<false><<<gg, 256, 0, stream>>>(vb, wvb, bv, Vp, 1.0f);

  transpose_v_kernel<<<dim3(32, 32), 256, 0, stream>>>(Vp, Vtg);

  float* outp = (float*)d_out;
  float* attnp = outp + 4194304;
  attn_kernel<<<dim3(32, 16, 2), 256, 0, stream>>>(Qp, Kp, Vtg, msk, attnp, Ob);

  gemm_bt_kernel<true><<<gg, 256, 0, stream>>>(Ob, wob, bo, outp, 1.0f);
}

// Round 5
// 612.625 us; speedup vs baseline: 1.0392x; 1.0392x over previous
//
#include <hip/hip_runtime.h>
#include <hip/hip_bf16.h>

// MultiHeadAttention fused pipeline for MI355X (gfx950).
// b=2, t=s=2048, E=1024, H=16, D=64. Outputs: out fp32 [2,2048,1024], attn fp32 [32,2048,2048].

typedef __attribute__((ext_vector_type(8))) __bf16 bf16x8;
typedef __attribute__((ext_vector_type(4))) float f32x4;
typedef __attribute__((ext_vector_type(8))) unsigned short us8;

#define MFMA16(A, B, C) __builtin_amdgcn_mfma_f32_16x16x32_bf16(A, B, C, 0, 0, 0)

__device__ __forceinline__ unsigned short f2bf(float f) {
  __bf16 h = (__bf16)f;
  return __builtin_bit_cast(unsigned short, h);
}
__device__ __forceinline__ bf16x8 u2b(uint4 u) { return __builtin_bit_cast(bf16x8, u); }

// ---------------- fused fp32 -> bf16 convert for all 7 tensors ----------------
__global__ __launch_bounds__(256) void cvt_all_kernel(
    const float* __restrict__ q, const float* __restrict__ k, const float* __restrict__ v,
    const float* __restrict__ Wq, const float* __restrict__ Wk,
    const float* __restrict__ Wv, const float* __restrict__ Wo,
    unsigned short* __restrict__ qb, unsigned short* __restrict__ kb,
    unsigned short* __restrict__ vb, unsigned short* __restrict__ wqb,
    unsigned short* __restrict__ wkb, unsigned short* __restrict__ wvb,
    unsigned short* __restrict__ wob) {
  const int bid = blockIdx.x;
  const float* src;
  unsigned short* dst;
  int i;
  if (bid < 4096)       { src = q; dst = qb; i = bid * 256 + threadIdx.x; }
  else if (bid < 8192)  { src = k; dst = kb; i = (bid - 4096) * 256 + threadIdx.x; }
  else if (bid < 12288) { src = v; dst = vb; i = (bid - 8192) * 256 + threadIdx.x; }
  else {
    int wsel = (bid - 12288) >> 10;
    i = ((bid - 12288) & 1023) * 256 + threadIdx.x;
    src = wsel == 0 ? Wq : wsel == 1 ? Wk : wsel == 2 ? Wv : Wo;
    dst = wsel == 0 ? wqb : wsel == 1 ? wkb : wsel == 2 ? wvb : wob;
  }
  float4 vv = ((const float4*)src)[i];
  ushort4 o;
  o.x = f2bf(vv.x); o.y = f2bf(vv.y); o.z = f2bf(vv.z); o.w = f2bf(vv.w);
  ((ushort4*)dst)[i] = o;
}

// ---------------- GEMM body: C[128x64 tile] = A @ W^T + bias, *scale ----------
template <bool OUT_F32>
__device__ __forceinline__ void gemm_body(
    const unsigned short* __restrict__ A, const unsigned short* __restrict__ Bw,
    const float* __restrict__ bias, void* __restrict__ Cout, float scale,
    int m0, int n0) {
  __shared__ short As[128 * 72];
  __shared__ short Bs[64 * 72];
  const int tid = threadIdx.x;
  const int l = tid & 63, w = tid >> 6;
  const int lq = l >> 4, lr = l & 15;

  uint4 va[4], vb[2];
#pragma unroll
  for (int i = 0; i < 4; ++i) {
    int c = i * 256 + tid, r = c >> 3, c8 = c & 7;
    va[i] = *(const uint4*)(A + (size_t)(m0 + r) * 1024 + c8 * 8);
  }
#pragma unroll
  for (int i = 0; i < 2; ++i) {
    int c = i * 256 + tid, r = c >> 3, c8 = c & 7;
    vb[i] = *(const uint4*)(Bw + (size_t)(n0 + r) * 1024 + c8 * 8);
  }
  const f32x4 fz = {0.f, 0.f, 0.f, 0.f};
  f32x4 acc[2][4];
#pragma unroll
  for (int m = 0; m < 2; ++m)
#pragma unroll
    for (int n = 0; n < 4; ++n) acc[m][n] = fz;

  for (int ks = 0; ks < 16; ++ks) {
    __syncthreads();
#pragma unroll
    for (int i = 0; i < 4; ++i) {
      int c = i * 256 + tid, r = c >> 3, c8 = c & 7;
      *(uint4*)((char*)As + r * 144 + c8 * 16) = va[i];
    }
#pragma unroll
    for (int i = 0; i < 2; ++i) {
      int c = i * 256 + tid, r = c >> 3, c8 = c & 7;
      *(uint4*)((char*)Bs + r * 144 + c8 * 16) = vb[i];
    }
    __syncthreads();
    if (ks < 15) {
      int k0 = (ks + 1) * 64;
#pragma unroll
      for (int i = 0; i < 4; ++i) {
        int c = i * 256 + tid, r = c >> 3, c8 = c & 7;
        va[i] = *(const uint4*)(A + (size_t)(m0 + r) * 1024 + k0 + c8 * 8);
      }
#pragma unroll
      for (int i = 0; i < 2; ++i) {
        int c = i * 256 + tid, r = c >> 3, c8 = c & 7;
        vb[i] = *(const uint4*)(Bw + (size_t)(n0 + r) * 1024 + k0 + c8 * 8);
      }
    }
#pragma unroll
    for (int kk = 0; kk < 2; ++kk) {
      bf16x8 af[2], bfr[4];
#pragma unroll
      for (int m = 0; m < 2; ++m)
        af[m] = *(const bf16x8*)((const char*)As + (w * 32 + m * 16 + lr) * 144 + kk * 64 + lq * 16);
#pragma unroll
      for (int n = 0; n < 4; ++n)
        bfr[n] = *(const bf16x8*)((const char*)Bs + (n * 16 + lr) * 144 + kk * 64 + lq * 16);
#pragma unroll
      for (int m = 0; m < 2; ++m)
#pragma unroll
        for (int n = 0; n < 4; ++n) acc[m][n] = MFMA16(af[m], bfr[n], acc[m][n]);
    }
  }
  // epilogue: C row = (lane>>4)*4+reg, col = lane&15
#pragma unroll
  for (int n = 0; n < 4; ++n) {
    const int col = n0 + n * 16 + lr;
    const float bv_ = bias[col];
#pragma unroll
    for (int m = 0; m < 2; ++m) {
      const int rowb = m0 + w * 32 + m * 16 + lq * 4;
#pragma unroll
      for (int r = 0; r < 4; ++r) {
        float vv = (acc[m][n][r] + bv_) * scale;
        if (OUT_F32)
          ((float*)Cout)[(size_t)(rowb + r) * 1024 + col] = vv;
        else
          ((unsigned short*)Cout)[(size_t)(rowb + r) * 1024 + col] = f2bf(vv);
      }
    }
  }
}

// merged Q/K/V projection: blockIdx.z selects which projection
__global__ __launch_bounds__(256) void gemm_qkv_kernel(
    const unsigned short* __restrict__ qb, const unsigned short* __restrict__ kb,
    const unsigned short* __restrict__ vb,
    const unsigned short* __restrict__ wqb, const unsigned short* __restrict__ wkb,
    const unsigned short* __restrict__ wvb,
    const float* __restrict__ bq, const float* __restrict__ bk, const float* __restrict__ bv,
    unsigned short* __restrict__ Qp, unsigned short* __restrict__ Kp,
    unsigned short* __restrict__ Vp) {
  const int z = blockIdx.z;
  const unsigned short* A = z == 0 ? qb : z == 1 ? kb : vb;
  const unsigned short* W = z == 0 ? wqb : z == 1 ? wkb : wvb;
  const float* bias = z == 0 ? bq : z == 1 ? bk : bv;
  unsigned short* C = z == 0 ? Qp : z == 1 ? Kp : Vp;
  const float scale = z == 0 ? 0.125f : 1.0f;
  gemm_body<false>(A, W, bias, C, scale, blockIdx.x * 128, blockIdx.y * 64);
}

__global__ __launch_bounds__(256) void gemm_o_kernel(
    const unsigned short* __restrict__ A, const unsigned short* __restrict__ Bw,
    const float* __restrict__ bias, float* __restrict__ Cout) {
  gemm_body<true>(A, Bw, bias, Cout, 1.0f, blockIdx.x * 128, blockIdx.y * 64);
}

// ---------------- V' [b*2048+key][h*64+d] -> Vt [(b*16+h)*64+d][key] ----------------
__global__ __launch_bounds__(256) void transpose_v_kernel(const unsigned short* __restrict__ Vp,
                                                          unsigned short* __restrict__ Vt) {
  __shared__ unsigned short Ts[64 * 72];
  const int tid = threadIdx.x;
  const int kt = blockIdx.x;
  const int rt = blockIdx.y;
  const int b_ = rt >> 4, h_ = rt & 15;
#pragma unroll
  for (int i = 0; i < 2; ++i) {
    int c = i * 256 + tid, r = c >> 3, c8 = c & 7;
    uint4 v = *(const uint4*)(Vp + (size_t)(b_ * 2048 + kt * 64 + r) * 1024 + h_ * 64 + c8 * 8);
    *(uint4*)((char*)Ts + r * 144 + c8 * 16) = v;
  }
  __syncthreads();
#pragma unroll
  for (int i = 0; i < 2; ++i) {
    int c = i * 256 + tid, dr = c >> 3, k8 = c & 7;
    us8 t8;
#pragma unroll
    for (int j = 0; j < 8; ++j) t8[j] = Ts[(k8 * 8 + j) * 72 + dr];
    *(us8*)(Vt + (size_t)(rt * 64 + dr) * 2048 + kt * 64 + k8 * 8) = t8;
  }
}

// ---------------- fused attention ----------------
// block = (b,h, 64 query rows); 4 waves x 16 rows. Two passes over 32 key-chunks of 64.
// K/V fragments read directly from global (L1/L2-resident) with issue-early/use-late
// register prefetch (static-indexed buffers). Pass A barrier-free, 2-chunk software
// pipeline. Pass B: double-buffered Pf (XOR-swizzled fp32 P tile) -> 1 barrier per chunk;
// coalesced nontemporal full-line stores; PV A-frag re-read from Pf.
// LDS 40960 B: [Pf0 16384 | Pf1 16384 | mask 8192]; Qs (init-only) overlaps Pf0.
__device__ __forceinline__ int pf_idx(int row, int col) {
  return row * 64 + (((col >> 2) ^ (row & 7)) << 2) + (col & 3);
}

__global__ __launch_bounds__(256) void attn_kernel(
    const unsigned short* __restrict__ Qp,  // [4096][1024] bf16 (pre-scaled)
    const unsigned short* __restrict__ Kp,  // [4096][1024] bf16
    const unsigned short* __restrict__ Vt,  // [2048][2048] bf16, row=(b*16+h)*64+d, col=key
    const int* __restrict__ mask,           // [2][2048]
    float* __restrict__ attn_out,           // [32][2048][2048] fp32
    unsigned short* __restrict__ Obuf)      // [4096][1024] bf16
{
  __shared__ char smem[40960];
  short* Qs = (short*)smem;                 // 9216 B, init only (overlaps Pf0)
  float* maskadd = (float*)(smem + 32768);  // 8192 B

  const int tid = threadIdx.x;
  const int l = tid & 63, w = tid >> 6;
  const int lq = l >> 4, lr = l & 15;
  const int tb = blockIdx.x, h = blockIdx.y, bz = blockIdx.z;

  const size_t qrow0 = (size_t)bz * 2048 + tb * 64;
  const size_t krow0 = (size_t)bz * 2048;
  const size_t vrow0 = (size_t)(bz * 16 + h) * 64;

  // preload additive mask for the whole key range
  for (int j = tid; j < 2048; j += 256) {
    int mv = mask[bz * 2048 + j];
    maskadd[j] = (mv == 0) ? -9.0e15f : (float)mv;
  }
  // stage Q block [64][64] -> Qs (stride 72), then pull fragments to registers
#pragma unroll
  for (int i = 0; i < 2; ++i) {
    int c = i * 256 + tid, r = c >> 3, c8 = c & 7;
    uint4 v = *(const uint4*)(Qp + (qrow0 + r) * 1024 + h * 64 + c8 * 8);
    *(uint4*)((char*)Qs + r * 144 + c8 * 16) = v;
  }
  __syncthreads();
  bf16x8 aq[2];
#pragma unroll
  for (int kk = 0; kk < 2; ++kk)
    aq[kk] = *(const bf16x8*)((const char*)Qs + (w * 16 + lr) * 144 + kk * 64 + lq * 16);
  __syncthreads();  // Qs dead; Pf0 may be written from here on

  const unsigned short* kbase = Kp + krow0 * 1024 + h * 64;
  const unsigned short* vbase = Vt + vrow0 * 2048;

#define LOADK(dst, kcv)                                                                  \
  {                                                                                      \
    _Pragma("unroll") for (int jt = 0; jt < 4; ++jt) {                                   \
      _Pragma("unroll") for (int kk = 0; kk < 2; ++kk) {                                 \
        dst[jt * 2 + kk] =                                                               \
            *(const uint4*)(kbase + (size_t)((kcv)*64 + jt * 16 + lr) * 1024 + kk * 32 + \
                            lq * 8);                                                     \
      }                                                                                  \
    }                                                                                    \
  }
#define LOADV(dst, kcv)                                                                 \
  {                                                                                     \
    _Pragma("unroll") for (int dt = 0; dt < 4; ++dt) {                                  \
      _Pragma("unroll") for (int kk = 0; kk < 2; ++kk) {                                \
        dst[dt * 2 + kk] = *(const uint4*)(vbase + (size_t)(dt * 16 + lr) * 2048 +      \
                                           (kcv)*64 + kk * 32 + lq * 8);                \
      }                                                                                 \
    }                                                                                   \
  }
#define COMPA(frag, kcv)                                                  \
  {                                                                       \
    _Pragma("unroll") for (int jt = 0; jt < 4; ++jt) {                    \
      f32x4 sa = {0.f, 0.f, 0.f, 0.f};                                    \
      sa = MFMA16(aq[0], u2b(frag[jt * 2 + 0]), sa);                      \
      sa = MFMA16(aq[1], u2b(frag[jt * 2 + 1]), sa);                      \
      float ma = maskadd[(kcv)*64 + jt * 16 + lr];                        \
      _Pragma("unroll") for (int r = 0; r < 4; ++r) {                     \
        float s_ = fminf(fmaxf(sa[r], -50000.f), 50000.f) + ma;           \
        lacc[r] += __expf(s_);                                            \
      }                                                                   \
    }                                                                     \
  }

  // ---------- pass A: denominators (barrier-free, 2-chunk pipelined) ----------
  float lacc[4] = {0.f, 0.f, 0.f, 0.f};
  {
    uint4 ka[8], kb2[8];
    LOADK(ka, 0);
    for (int kc2 = 0; kc2 < 32; kc2 += 2) {
      LOADK(kb2, kc2 + 1);
      COMPA(ka, kc2);
      if (kc2 + 2 < 32) LOADK(ka, kc2 + 2);
      COMPA(kb2, kc2 + 1);
    }
  }
#pragma unroll
  for (int r = 0; r < 4; ++r) {
    float t = lacc[r];
    t += __shfl_xor(t, 1, 64);
    t += __shfl_xor(t, 2, 64);
    t += __shfl_xor(t, 4, 64);
    t += __shfl_xor(t, 8, 64);
    lacc[r] = 1.0f / t;  // reciprocal denominator for row lq*4+r
  }

  // ---------- pass B: write attn (coalesced via Pf dbuf) + PV ----------
  const f32x4 fz = {0.f, 0.f, 0.f, 0.f};
  f32x4 oacc[4];
#pragma unroll
  for (int dt = 0; dt < 4; ++dt) oacc[dt] = fz;
  const size_t arow = (size_t)(bz * 16 + h) * 2048 + tb * 64;

  uint4 ka[8], vv[8];
  LOADK(ka, 0);
  LOADV(vv, 0);
  for (int kc = 0; kc < 32; ++kc) {
    float* Pfc = (float*)(smem + ((kc & 1) << 14));
    // QK^T + exp + Pf write (uses ka = K[kc])
#pragma unroll
    for (int jt = 0; jt < 4; ++jt) {
      f32x4 sa = {0.f, 0.f, 0.f, 0.f};
      sa = MFMA16(aq[0], u2b(ka[jt * 2 + 0]), sa);
      sa = MFMA16(aq[1], u2b(ka[jt * 2 + 1]), sa);
      float ma = maskadd[kc * 64 + jt * 16 + lr];
#pragma unroll
      for (int r = 0; r < 4; ++r) {
        float s_ = fminf(fmaxf(sa[r], -50000.f), 50000.f) + ma;
        float p = __expf(s_) * lacc[r];
        Pfc[pf_idx(w * 16 + lq * 4 + r, jt * 16 + lr)] = p;
      }
    }
    if (kc < 31) LOADK(ka, kc + 1);  // issue-early: used next iteration
    __syncthreads();                 // Pfc complete
    // cooperative full-line nontemporal stores: 16 KB contiguous per block-chunk
#pragma unroll
    for (int it = 0; it < 4; ++it) {
      int idx = it * 256 + tid, row = idx >> 4, c4 = idx & 15;
      f32x4 pv4 = *(const f32x4*)&Pfc[pf_idx(row, c4 * 4)];
      f32x4* dst = (f32x4*)&attn_out[(arow + row) * 2048 + kc * 64 + c4 * 4];
      __builtin_nontemporal_store(pv4, dst);
    }
    // PV: A-frag = this wave's 16 P-rows from Pfc (cvt fp32->bf16); B = vv = V[kc]
#pragma unroll
    for (int kk = 0; kk < 2; ++kk) {
      const int prow = w * 16 + lr;
      f32x4 a0 = *(const f32x4*)&Pfc[pf_idx(prow, kk * 32 + lq * 8)];
      f32x4 a1 = *(const f32x4*)&Pfc[pf_idx(prow, kk * 32 + lq * 8 + 4)];
      bf16x8 ap;
#pragma unroll
      for (int j = 0; j < 4; ++j) {
        ap[j] = (__bf16)a0[j];
        ap[4 + j] = (__bf16)a1[j];
      }
#pragma unroll
      for (int dt = 0; dt < 4; ++dt)
        oacc[dt] = MFMA16(ap, u2b(vv[dt * 2 + kk]), oacc[dt]);
    }
    if (kc < 31) LOADV(vv, kc + 1);  // issue-early: used next iteration
    // no trailing barrier needed: next chunk writes the OTHER Pf buffer; this
    // buffer's next write (kc+2) is separated by kc+1's barrier.
  }
  // write O (bf16) in [b*2048+t][h*64+d] layout for the final projection
#pragma unroll
  for (int dt = 0; dt < 4; ++dt) {
    int col = h * 64 + dt * 16 + lr;
#pragma unroll
    for (int r = 0; r < 4; ++r) {
      int trow = tb * 64 + w * 16 + lq * 4 + r;
      Obuf[((size_t)bz * 2048 + trow) * 1024 + col] = f2bf(oacc[dt][r]);
    }
  }
#undef LOADK
#undef LOADV
#undef COMPA
}

extern "C" void kernel_launch(void* const* d_in, const int* in_sizes, int n_in,
                              void* d_out, int out_size, void* d_ws, size_t ws_size,
                              hipStream_t stream) {
  (void)in_sizes; (void)n_in; (void)out_size; (void)ws_size;
  const float* q  = (const float*)d_in[0];
  const float* k  = (const float*)d_in[1];
  const float* v  = (const float*)d_in[2];
  const int* msk  = (const int*)d_in[3];
  const float* Wq = (const float*)d_in[4];
  const float* bq = (const float*)d_in[5];
  const float* Wk = (const float*)d_in[6];
  const float* bk = (const float*)d_in[7];
  const float* Wv = (const float*)d_in[8];
  const float* bv = (const float*)d_in[9];
  const float* Wo = (const float*)d_in[10];
  const float* bo = (const float*)d_in[11];

  // workspace layout (bf16 elements), total ~72 MB
  unsigned short* p = (unsigned short*)d_ws;
  unsigned short* qb  = p; p += 4194304;
  unsigned short* kb  = p; p += 4194304;
  unsigned short* vb  = p; p += 4194304;
  unsigned short* wqb = p; p += 1048576;
  unsigned short* wkb = p; p += 1048576;
  unsigned short* wvb = p; p += 1048576;
  unsigned short* wob = p; p += 1048576;
  unsigned short* Qp  = p; p += 4194304;
  unsigned short* Kp  = p; p += 4194304;
  unsigned short* Vp  = p; p += 4194304;
  unsigned short* Vtg = p; p += 4194304;
  unsigned short* Ob  = p; p += 4194304;

  cvt_all_kernel<<<16384, 256, 0, stream>>>(q, k, v, Wq, Wk, Wv, Wo,
                                            qb, kb, vb, wqb, wkb, wvb, wob);

  gemm_qkv_kernel<<<dim3(32, 16, 3), 256, 0, stream>>>(qb, kb, vb, wqb, wkb, wvb,
                                                       bq, bk, bv, Qp, Kp, Vp);

  transpose_v_kernel<<<dim3(32, 32), 256, 0, stream>>>(Vp, Vtg);

  float* outp = (float*)d_out;
  float* attnp = outp + 4194304;
  attn_kernel<<<dim3(32, 16, 2), 256, 0, stream>>>(Qp, Kp, Vtg, msk, attnp, Ob);

  gemm_o_kernel<<<dim3(32, 16), 256, 0, stream>>>(Ob, wob, bo, outp);
}

// Round 6
// 607.527 us; speedup vs baseline: 1.0479x; 1.0084x over previous
//
#include <hip/hip_runtime.h>
#include <hip/hip_bf16.h>

// MultiHeadAttention fused pipeline for MI355X (gfx950).
// b=2, t=s=2048, E=1024, H=16, D=64. Outputs: out fp32 [2,2048,1024], attn fp32 [32,2048,2048].

typedef __attribute__((ext_vector_type(8))) __bf16 bf16x8;
typedef __attribute__((ext_vector_type(4))) float f32x4;
typedef __attribute__((ext_vector_type(8))) unsigned short us8;

#define MFMA16(A, B, C) __builtin_amdgcn_mfma_f32_16x16x32_bf16(A, B, C, 0, 0, 0)

__device__ __forceinline__ unsigned short f2bf(float f) {
  __bf16 h = (__bf16)f;
  return __builtin_bit_cast(unsigned short, h);
}
__device__ __forceinline__ bf16x8 u2b(uint4 u) { return __builtin_bit_cast(bf16x8, u); }

// ---------------- fused fp32 -> bf16 convert for all 7 tensors ----------------
__global__ __launch_bounds__(256) void cvt_all_kernel(
    const float* __restrict__ q, const float* __restrict__ k, const float* __restrict__ v,
    const float* __restrict__ Wq, const float* __restrict__ Wk,
    const float* __restrict__ Wv, const float* __restrict__ Wo,
    unsigned short* __restrict__ qb, unsigned short* __restrict__ kb,
    unsigned short* __restrict__ vb, unsigned short* __restrict__ wqb,
    unsigned short* __restrict__ wkb, unsigned short* __restrict__ wvb,
    unsigned short* __restrict__ wob) {
  const int bid = blockIdx.x;
  const float* src;
  unsigned short* dst;
  int i;
  if (bid < 4096)       { src = q; dst = qb; i = bid * 256 + threadIdx.x; }
  else if (bid < 8192)  { src = k; dst = kb; i = (bid - 4096) * 256 + threadIdx.x; }
  else if (bid < 12288) { src = v; dst = vb; i = (bid - 8192) * 256 + threadIdx.x; }
  else {
    int wsel = (bid - 12288) >> 10;
    i = ((bid - 12288) & 1023) * 256 + threadIdx.x;
    src = wsel == 0 ? Wq : wsel == 1 ? Wk : wsel == 2 ? Wv : Wo;
    dst = wsel == 0 ? wqb : wsel == 1 ? wkb : wsel == 2 ? wvb : wob;
  }
  float4 vv = ((const float4*)src)[i];
  ushort4 o;
  o.x = f2bf(vv.x); o.y = f2bf(vv.y); o.z = f2bf(vv.z); o.w = f2bf(vv.w);
  ((ushort4*)dst)[i] = o;
}

// ---------------- GEMM body: C[128x64 tile] = A @ W^T + bias, *scale ----------
template <bool OUT_F32>
__device__ __forceinline__ void gemm_body(
    const unsigned short* __restrict__ A, const unsigned short* __restrict__ Bw,
    const float* __restrict__ bias, void* __restrict__ Cout, float scale,
    int m0, int n0) {
  __shared__ short As[128 * 72];
  __shared__ short Bs[64 * 72];
  const int tid = threadIdx.x;
  const int l = tid & 63, w = tid >> 6;
  const int lq = l >> 4, lr = l & 15;

  uint4 va[4], vb[2];
#pragma unroll
  for (int i = 0; i < 4; ++i) {
    int c = i * 256 + tid, r = c >> 3, c8 = c & 7;
    va[i] = *(const uint4*)(A + (size_t)(m0 + r) * 1024 + c8 * 8);
  }
#pragma unroll
  for (int i = 0; i < 2; ++i) {
    int c = i * 256 + tid, r = c >> 3, c8 = c & 7;
    vb[i] = *(const uint4*)(Bw + (size_t)(n0 + r) * 1024 + c8 * 8);
  }
  const f32x4 fz = {0.f, 0.f, 0.f, 0.f};
  f32x4 acc[2][4];
#pragma unroll
  for (int m = 0; m < 2; ++m)
#pragma unroll
    for (int n = 0; n < 4; ++n) acc[m][n] = fz;

  for (int ks = 0; ks < 16; ++ks) {
    __syncthreads();
#pragma unroll
    for (int i = 0; i < 4; ++i) {
      int c = i * 256 + tid, r = c >> 3, c8 = c & 7;
      *(uint4*)((char*)As + r * 144 + c8 * 16) = va[i];
    }
#pragma unroll
    for (int i = 0; i < 2; ++i) {
      int c = i * 256 + tid, r = c >> 3, c8 = c & 7;
      *(uint4*)((char*)Bs + r * 144 + c8 * 16) = vb[i];
    }
    __syncthreads();
    if (ks < 15) {
      int k0 = (ks + 1) * 64;
#pragma unroll
      for (int i = 0; i < 4; ++i) {
        int c = i * 256 + tid, r = c >> 3, c8 = c & 7;
        va[i] = *(const uint4*)(A + (size_t)(m0 + r) * 1024 + k0 + c8 * 8);
      }
#pragma unroll
      for (int i = 0; i < 2; ++i) {
        int c = i * 256 + tid, r = c >> 3, c8 = c & 7;
        vb[i] = *(const uint4*)(Bw + (size_t)(n0 + r) * 1024 + k0 + c8 * 8);
      }
    }
#pragma unroll
    for (int kk = 0; kk < 2; ++kk) {
      bf16x8 af[2], bfr[4];
#pragma unroll
      for (int m = 0; m < 2; ++m)
        af[m] = *(const bf16x8*)((const char*)As + (w * 32 + m * 16 + lr) * 144 + kk * 64 + lq * 16);
#pragma unroll
      for (int n = 0; n < 4; ++n)
        bfr[n] = *(const bf16x8*)((const char*)Bs + (n * 16 + lr) * 144 + kk * 64 + lq * 16);
#pragma unroll
      for (int m = 0; m < 2; ++m)
#pragma unroll
        for (int n = 0; n < 4; ++n) acc[m][n] = MFMA16(af[m], bfr[n], acc[m][n]);
    }
  }
  // epilogue: C row = (lane>>4)*4+reg, col = lane&15
#pragma unroll
  for (int n = 0; n < 4; ++n) {
    const int col = n0 + n * 16 + lr;
    const float bv_ = bias[col];
#pragma unroll
    for (int m = 0; m < 2; ++m) {
      const int rowb = m0 + w * 32 + m * 16 + lq * 4;
#pragma unroll
      for (int r = 0; r < 4; ++r) {
        float vv = (acc[m][n][r] + bv_) * scale;
        if (OUT_F32)
          ((float*)Cout)[(size_t)(rowb + r) * 1024 + col] = vv;
        else
          ((unsigned short*)Cout)[(size_t)(rowb + r) * 1024 + col] = f2bf(vv);
      }
    }
  }
}

// merged Q/K/V projection: blockIdx.z selects which projection
__global__ __launch_bounds__(256) void gemm_qkv_kernel(
    const unsigned short* __restrict__ qb, const unsigned short* __restrict__ kb,
    const unsigned short* __restrict__ vb,
    const unsigned short* __restrict__ wqb, const unsigned short* __restrict__ wkb,
    const unsigned short* __restrict__ wvb,
    const float* __restrict__ bq, const float* __restrict__ bk, const float* __restrict__ bv,
    unsigned short* __restrict__ Qp, unsigned short* __restrict__ Kp,
    unsigned short* __restrict__ Vp) {
  const int z = blockIdx.z;
  const unsigned short* A = z == 0 ? qb : z == 1 ? kb : vb;
  const unsigned short* W = z == 0 ? wqb : z == 1 ? wkb : wvb;
  const float* bias = z == 0 ? bq : z == 1 ? bk : bv;
  unsigned short* C = z == 0 ? Qp : z == 1 ? Kp : Vp;
  const float scale = z == 0 ? 0.125f : 1.0f;
  gemm_body<false>(A, W, bias, C, scale, blockIdx.x * 128, blockIdx.y * 64);
}

__global__ __launch_bounds__(256) void gemm_o_kernel(
    const unsigned short* __restrict__ A, const unsigned short* __restrict__ Bw,
    const float* __restrict__ bias, float* __restrict__ Cout) {
  gemm_body<true>(A, Bw, bias, Cout, 1.0f, blockIdx.x * 128, blockIdx.y * 64);
}

// ---------------- V' [b*2048+key][h*64+d] -> Vt [(b*16+h)*64+d][key] ----------------
__global__ __launch_bounds__(256) void transpose_v_kernel(const unsigned short* __restrict__ Vp,
                                                          unsigned short* __restrict__ Vt) {
  __shared__ unsigned short Ts[64 * 72];
  const int tid = threadIdx.x;
  const int kt = blockIdx.x;
  const int rt = blockIdx.y;
  const int b_ = rt >> 4, h_ = rt & 15;
#pragma unroll
  for (int i = 0; i < 2; ++i) {
    int c = i * 256 + tid, r = c >> 3, c8 = c & 7;
    uint4 v = *(const uint4*)(Vp + (size_t)(b_ * 2048 + kt * 64 + r) * 1024 + h_ * 64 + c8 * 8);
    *(uint4*)((char*)Ts + r * 144 + c8 * 16) = v;
  }
  __syncthreads();
#pragma unroll
  for (int i = 0; i < 2; ++i) {
    int c = i * 256 + tid, dr = c >> 3, k8 = c & 7;
    us8 t8;
#pragma unroll
    for (int j = 0; j < 8; ++j) t8[j] = Ts[(k8 * 8 + j) * 72 + dr];
    *(us8*)(Vt + (size_t)(rt * 64 + dr) * 2048 + kt * 64 + k8 * 8) = t8;
  }
}

// ---------------- fused attention (fully barrier-free main loops) ----------------
// block = (b,h, 64 query rows); 4 waves x 16 rows, each wave INDEPENDENT.
// K/V fragments read directly from global (L1/L2-resident) with register prefetch.
// Pass A: denominators, barrier-free, 2-chunk pipelined.
// Pass B: per-wave PRIVATE 4KB swizzled Pf tile (intra-wave LDS dep = lgkmcnt only,
// no __syncthreads): write P fp32 -> read back f32x4 rows for 256B-segment (all
// full-line) nontemporal stores + read/cvt bf16 A-frags for PV MFMA.
// LDS 24576 B: [4 x 4096 wave Pf | mask 8192]; Qs (init-only) overlaps Pf.
__device__ __forceinline__ int pf_idx(int row, int col) {
  return row * 64 + (((col >> 2) ^ (row & 7)) << 2) + (col & 3);
}

__global__ __launch_bounds__(256) void attn_kernel(
    const unsigned short* __restrict__ Qp,  // [4096][1024] bf16 (pre-scaled)
    const unsigned short* __restrict__ Kp,  // [4096][1024] bf16
    const unsigned short* __restrict__ Vt,  // [2048][2048] bf16, row=(b*16+h)*64+d, col=key
    const int* __restrict__ mask,           // [2][2048]
    float* __restrict__ attn_out,           // [32][2048][2048] fp32
    unsigned short* __restrict__ Obuf)      // [4096][1024] bf16
{
  __shared__ char smem[24576];
  short* Qs = (short*)smem;                 // 9216 B, init only (overlaps wave Pf)
  float* maskadd = (float*)(smem + 16384);  // 8192 B

  const int tid = threadIdx.x;
  const int l = tid & 63, w = tid >> 6;
  const int lq = l >> 4, lr = l & 15;
  float* Pw = (float*)(smem + w * 4096);    // wave-private 16x64 fp32 tile

  const int tb = blockIdx.x, h = blockIdx.y, bz = blockIdx.z;

  const size_t qrow0 = (size_t)bz * 2048 + tb * 64;
  const size_t krow0 = (size_t)bz * 2048;
  const size_t vrow0 = (size_t)(bz * 16 + h) * 64;

  // preload additive mask for the whole key range
  for (int j = tid; j < 2048; j += 256) {
    int mv = mask[bz * 2048 + j];
    maskadd[j] = (mv == 0) ? -9.0e15f : (float)mv;
  }
  // stage Q block [64][64] -> Qs (stride 72), then pull fragments to registers
#pragma unroll
  for (int i = 0; i < 2; ++i) {
    int c = i * 256 + tid, r = c >> 3, c8 = c & 7;
    uint4 v = *(const uint4*)(Qp + (qrow0 + r) * 1024 + h * 64 + c8 * 8);
    *(uint4*)((char*)Qs + r * 144 + c8 * 16) = v;
  }
  __syncthreads();
  bf16x8 aq[2];
#pragma unroll
  for (int kk = 0; kk < 2; ++kk)
    aq[kk] = *(const bf16x8*)((const char*)Qs + (w * 16 + lr) * 144 + kk * 64 + lq * 16);
  __syncthreads();  // Qs dead; wave-private Pf regions usable from here on

  const unsigned short* kbase = Kp + krow0 * 1024 + h * 64;
  const unsigned short* vbase = Vt + vrow0 * 2048;

#define LOADK(dst, kcv)                                                                  \
  {                                                                                      \
    _Pragma("unroll") for (int jt = 0; jt < 4; ++jt) {                                   \
      _Pragma("unroll") for (int kk = 0; kk < 2; ++kk) {                                 \
        dst[jt * 2 + kk] =                                                               \
            *(const uint4*)(kbase + (size_t)((kcv)*64 + jt * 16 + lr) * 1024 + kk * 32 + \
                            lq * 8);                                                     \
      }                                                                                  \
    }                                                                                    \
  }
#define LOADV(dst, kcv)                                                                 \
  {                                                                                     \
    _Pragma("unroll") for (int dt = 0; dt < 4; ++dt) {                                  \
      _Pragma("unroll") for (int kk = 0; kk < 2; ++kk) {                                \
        dst[dt * 2 + kk] = *(const uint4*)(vbase + (size_t)(dt * 16 + lr) * 2048 +      \
                                           (kcv)*64 + kk * 32 + lq * 8);                \
      }                                                                                 \
    }                                                                                   \
  }
#define COMPA(frag, kcv)                                                  \
  {                                                                       \
    _Pragma("unroll") for (int jt = 0; jt < 4; ++jt) {                    \
      f32x4 sa = {0.f, 0.f, 0.f, 0.f};                                    \
      sa = MFMA16(aq[0], u2b(frag[jt * 2 + 0]), sa);                      \
      sa = MFMA16(aq[1], u2b(frag[jt * 2 + 1]), sa);                      \
      float ma = maskadd[(kcv)*64 + jt * 16 + lr];                        \
      _Pragma("unroll") for (int r = 0; r < 4; ++r) {                     \
        float s_ = fminf(fmaxf(sa[r], -50000.f), 50000.f) + ma;           \
        lacc[r] += __expf(s_);                                            \
      }                                                                   \
    }                                                                     \
  }

  // ---------- pass A: denominators (barrier-free, 2-chunk pipelined) ----------
  float lacc[4] = {0.f, 0.f, 0.f, 0.f};
  {
    uint4 ka[8], kb2[8];
    LOADK(ka, 0);
    for (int kc2 = 0; kc2 < 32; kc2 += 2) {
      LOADK(kb2, kc2 + 1);
      COMPA(ka, kc2);
      if (kc2 + 2 < 32) LOADK(ka, kc2 + 2);
      COMPA(kb2, kc2 + 1);
    }
  }
#pragma unroll
  for (int r = 0; r < 4; ++r) {
    float t = lacc[r];
    t += __shfl_xor(t, 1, 64);
    t += __shfl_xor(t, 2, 64);
    t += __shfl_xor(t, 4, 64);
    t += __shfl_xor(t, 8, 64);
    lacc[r] = 1.0f / t;  // reciprocal denominator for row lq*4+r
  }

  // ---------- pass B: write attn (coalesced via wave-private Pf) + PV ----------
  const f32x4 fz = {0.f, 0.f, 0.f, 0.f};
  f32x4 oacc[4];
#pragma unroll
  for (int dt = 0; dt < 4; ++dt) oacc[dt] = fz;
  const size_t arow = (size_t)(bz * 16 + h) * 2048 + tb * 64 + w * 16;

  uint4 ka[8], vv[8];
  LOADK(ka, 0);
  LOADV(vv, 0);
  for (int kc = 0; kc < 32; ++kc) {
    // QK^T + exp + Pw write (uses ka = K[kc]); within-wave rows 0..15
#pragma unroll
    for (int jt = 0; jt < 4; ++jt) {
      f32x4 sa = {0.f, 0.f, 0.f, 0.f};
      sa = MFMA16(aq[0], u2b(ka[jt * 2 + 0]), sa);
      sa = MFMA16(aq[1], u2b(ka[jt * 2 + 1]), sa);
      float ma = maskadd[kc * 64 + jt * 16 + lr];
#pragma unroll
      for (int r = 0; r < 4; ++r) {
        float s_ = fminf(fmaxf(sa[r], -50000.f), 50000.f) + ma;
        float p = __expf(s_) * lacc[r];
        Pw[pf_idx(lq * 4 + r, jt * 16 + lr)] = p;
      }
    }
    if (kc < 31) LOADK(ka, kc + 1);  // issue-early: used next iteration
    // stores: 4 insts/wave, each 4 rows x 256B contiguous (all full 128B lines)
#pragma unroll
    for (int it = 0; it < 4; ++it) {
      int row = it * 4 + lq;
      f32x4 pv4 = *(const f32x4*)&Pw[pf_idx(row, lr * 4)];
      f32x4* dst = (f32x4*)&attn_out[(arow + row) * 2048 + kc * 64 + lr * 4];
      __builtin_nontemporal_store(pv4, dst);
    }
    // PV: A-frag = row lr, cols lq*8..+7 from Pw (cvt fp32->bf16); B = vv = V[kc]
#pragma unroll
    for (int kk = 0; kk < 2; ++kk) {
      f32x4 a0 = *(const f32x4*)&Pw[pf_idx(lr, kk * 32 + lq * 8)];
      f32x4 a1 = *(const f32x4*)&Pw[pf_idx(lr, kk * 32 + lq * 8 + 4)];
      bf16x8 ap;
#pragma unroll
      for (int j = 0; j < 4; ++j) {
        ap[j] = (__bf16)a0[j];
        ap[4 + j] = (__bf16)a1[j];
      }
#pragma unroll
      for (int dt = 0; dt < 4; ++dt)
        oacc[dt] = MFMA16(ap, u2b(vv[dt * 2 + kk]), oacc[dt]);
    }
    if (kc < 31) LOADV(vv, kc + 1);  // issue-early: used next iteration
    // no barrier: Pw is wave-private; intra-wave LDS ordering via lgkmcnt
  }
  // write O (bf16) in [b*2048+t][h*64+d] layout for the final projection
#pragma unroll
  for (int dt = 0; dt < 4; ++dt) {
    int col = h * 64 + dt * 16 + lr;
#pragma unroll
    for (int r = 0; r < 4; ++r) {
      int trow = tb * 64 + w * 16 + lq * 4 + r;
      Obuf[((size_t)bz * 2048 + trow) * 1024 + col] = f2bf(oacc[dt][r]);
    }
  }
#undef LOADK
#undef LOADV
#undef COMPA
}

extern "C" void kernel_launch(void* const* d_in, const int* in_sizes, int n_in,
                              void* d_out, int out_size, void* d_ws, size_t ws_size,
                              hipStream_t stream) {
  (void)in_sizes; (void)n_in; (void)out_size; (void)ws_size;
  const float* q  = (const float*)d_in[0];
  const float* k  = (const float*)d_in[1];
  const float* v  = (const float*)d_in[2];
  const int* msk  = (const int*)d_in[3];
  const float* Wq = (const float*)d_in[4];
  const float* bq = (const float*)d_in[5];
  const float* Wk = (const float*)d_in[6];
  const float* bk = (const float*)d_in[7];
  const float* Wv = (const float*)d_in[8];
  const float* bv = (const float*)d_in[9];
  const float* Wo = (const float*)d_in[10];
  const float* bo = (const float*)d_in[11];

  // workspace layout (bf16 elements), total ~72 MB
  unsigned short* p = (unsigned short*)d_ws;
  unsigned short* qb  = p; p += 4194304;
  unsigned short* kb  = p; p += 4194304;
  unsigned short* vb  = p; p += 4194304;
  unsigned short* wqb = p; p += 1048576;
  unsigned short* wkb = p; p += 1048576;
  unsigned short* wvb = p; p += 1048576;
  unsigned short* wob = p; p += 1048576;
  unsigned short* Qp  = p; p += 4194304;
  unsigned short* Kp  = p; p += 4194304;
  unsigned short* Vp  = p; p += 4194304;
  unsigned short* Vtg = p; p += 4194304;
  unsigned short* Ob  = p; p += 4194304;

  cvt_all_kernel<<<16384, 256, 0, stream>>>(q, k, v, Wq, Wk, Wv, Wo,
                                            qb, kb, vb, wqb, wkb, wvb, wob);

  gemm_qkv_kernel<<<dim3(32, 16, 3), 256, 0, stream>>>(qb, kb, vb, wqb, wkb, wvb,
                                                       bq, bk, bv, Qp, Kp, Vp);

  transpose_v_kernel<<<dim3(32, 32), 256, 0, stream>>>(Vp, Vtg);

  float* outp = (float*)d_out;
  float* attnp = outp + 4194304;
  attn_kernel<<<dim3(32, 16, 2), 256, 0, stream>>>(Qp, Kp, Vtg, msk, attnp, Ob);

  gemm_o_kernel<<<dim3(32, 16), 256, 0, stream>>>(Ob, wob, bo, outp);
}